// Round 10
// baseline (57.833 us; speedup 1.0000x reference)
//
#include <hip/hip_runtime.h>

// ConvDatapath: bit-serial crossbar conv with per-chunk ADC quantization.
// SINGLE kernel (one cold launch, fast replay). 1568 blocks x 256 thr:
// block = (rtile 0..391, cq 0..3) -> 16 x-rows x 2 w-tiles (32 output cols).
// Phases: A stage x -> B quant x -> C quant w (2 tiles, redundant per block,
// L2-served) -> D MFMA+ADC with K-split across wave pairs and 2-chunk ILP.
// Nx = 6272, Ny = 128, K = 576 (5 chunks of 116, padded to 128).

#define KDIM  576
#define NPB   116
#define SSTR  688    // scratch row stride: 43*16 -> b128-aligned, 172 dw % 32 = 12

typedef int i32x4 __attribute__((ext_vector_type(4)));
typedef float f32x4 __attribute__((ext_vector_type(4)));

__device__ __forceinline__ i32x4 slice2b(i32x4 v, int sh) {
    i32x4 r;
    r[0] = (int)(((unsigned)v[0] >> sh) & 0x03030303u);
    r[1] = (int)(((unsigned)v[1] >> sh) & 0x03030303u);
    r[2] = (int)(((unsigned)v[2] >> sh) & 0x03030303u);
    r[3] = (int)(((unsigned)v[3] >> sh) & 0x03030303u);
    return r;
}

// ADC: clip to 1024, round-half-even to multiple of 4, shift-accumulate.
__device__ __forceinline__ void adc_acc(const i32x4 d, int sh, i32x4& acc) {
#pragma unroll
    for (int r = 0; r < 4; r++) {
        int z = d[r];
        z = z > 1024 ? 1024 : z;                 // z >= 0 always
        int t = (z >> 2) & 1;
        int r4 = (z + 1 + t) & ~3;               // round-half-even, mult of 4
        acc[r] += r4 << sh;                      // 2^(ish+wsh)
    }
}

// quantize one row spread over a 16-lane group (lane i16 holds k=36*i16..+35,
// k-ordered). Stats via 4-step shuffle (exact); 9 dword-aligned b32 writes,
// col = k + 12*chunk (i.e. chunk*128 + k%116).
__device__ __forceinline__ void quant36(const float (&v)[36], unsigned char* rowp,
                                        int i16, float* sc, float* of,
                                        float* sm_, int sidx)
{
    float mn = v[0], mx = v[0], sm = 0.f;
#pragma unroll
    for (int m = 0; m < 36; m++) { mn = fminf(mn, v[m]); mx = fmaxf(mx, v[m]); sm += v[m]; }
#pragma unroll
    for (int off = 1; off < 16; off <<= 1) {
        mn = fminf(mn, __shfl_xor(mn, off));
        mx = fmaxf(mx, __shfl_xor(mx, off));
        sm += __shfl_xor(sm, off);
    }
    float step = (mx - mn) / 255.0f;
    if (i16 == 0) { sc[sidx] = step; of[sidx] = mn; sm_[sidx] = sm; }
    int k0 = i16 * 36;
#pragma unroll
    for (int d = 0; d < 9; d++) {
        unsigned int dw = 0;
#pragma unroll
        for (int mb = 0; mb < 4; mb++) {
            int q = (int)rintf((v[d * 4 + mb] - mn) / step);
            q = q < 0 ? 0 : (q > 255 ? 255 : q);
            dw |= (unsigned)q << (8 * mb);
        }
        int kd = k0 + d * 4;
        int ch = kd / NPB;
        *(unsigned int*)(rowp + kd + 12 * ch) = dw;
    }
}

// zero the K-pad dwords of scratch row (idx>>4), pad dword (idx&15)
__device__ __forceinline__ void zero_pad_row(unsigned char* scr, int idx) {
    int rl = idx >> 4, dwp = idx & 15;
    int col = dwp < 12 ? (dwp / 3) * 128 + 116 + (dwp % 3) * 4
                       : 624 + (dwp - 12) * 4;
    *(unsigned int*)(scr + rl * SSTR + col) = 0u;
}

// one chunk: 16 slice-pairs, chained 2xMFMA (full 128-K before ADC)
__device__ __forceinline__ void chunk1(const unsigned char* xp, const unsigned char* wp,
                                       int ch, i32x4& acc)
{
    const i32x4 zero = {0, 0, 0, 0};
    i32x4 x0 = *(const i32x4*)(xp + ch * 128);
    i32x4 x1 = *(const i32x4*)(xp + ch * 128 + 64);
    i32x4 w0 = *(const i32x4*)(wp + ch * 128);
    i32x4 w1 = *(const i32x4*)(wp + ch * 128 + 64);
    i32x4 ws0[4], ws1[4];
#pragma unroll
    for (int ws = 0; ws < 4; ws++) {
        ws0[ws] = slice2b(w0, 6 - 2 * ws);
        ws1[ws] = slice2b(w1, 6 - 2 * ws);
    }
#pragma unroll
    for (int is = 0; is < 4; is++) {
        int ish = 6 - 2 * is;
        i32x4 a0 = slice2b(x0, ish), a1 = slice2b(x1, ish);
#pragma unroll
        for (int ws = 0; ws < 4; ws++) {
            i32x4 d = __builtin_amdgcn_mfma_i32_16x16x64_i8(ws0[ws], a0, zero, 0, 0, 0);
            d = __builtin_amdgcn_mfma_i32_16x16x64_i8(ws1[ws], a1, d, 0, 0, 0);
            adc_acc(d, ish + 6 - 2 * ws, acc);
        }
    }
}

// two chunks interleaved: 2 independent MFMA->ADC chains in flight
__device__ __forceinline__ void chunk2(const unsigned char* xp, const unsigned char* wp,
                                       int ca, int cb, i32x4& acca, i32x4& accb)
{
    const i32x4 zero = {0, 0, 0, 0};
    i32x4 xa0 = *(const i32x4*)(xp + ca * 128);
    i32x4 xa1 = *(const i32x4*)(xp + ca * 128 + 64);
    i32x4 xc0 = *(const i32x4*)(xp + cb * 128);
    i32x4 xc1 = *(const i32x4*)(xp + cb * 128 + 64);
    i32x4 wa0 = *(const i32x4*)(wp + ca * 128);
    i32x4 wa1 = *(const i32x4*)(wp + ca * 128 + 64);
    i32x4 wc0 = *(const i32x4*)(wp + cb * 128);
    i32x4 wc1 = *(const i32x4*)(wp + cb * 128 + 64);
    i32x4 wsa0[4], wsa1[4], wsb0[4], wsb1[4];
#pragma unroll
    for (int ws = 0; ws < 4; ws++) {
        wsa0[ws] = slice2b(wa0, 6 - 2 * ws);
        wsa1[ws] = slice2b(wa1, 6 - 2 * ws);
        wsb0[ws] = slice2b(wc0, 6 - 2 * ws);
        wsb1[ws] = slice2b(wc1, 6 - 2 * ws);
    }
#pragma unroll
    for (int is = 0; is < 4; is++) {
        int ish = 6 - 2 * is;
        i32x4 a0 = slice2b(xa0, ish), a1 = slice2b(xa1, ish);
        i32x4 b0 = slice2b(xc0, ish), b1 = slice2b(xc1, ish);
#pragma unroll
        for (int ws = 0; ws < 4; ws++) {
            i32x4 da = __builtin_amdgcn_mfma_i32_16x16x64_i8(wsa0[ws], a0, zero, 0, 0, 0);
            i32x4 db = __builtin_amdgcn_mfma_i32_16x16x64_i8(wsb0[ws], b0, zero, 0, 0, 0);
            da = __builtin_amdgcn_mfma_i32_16x16x64_i8(wsa1[ws], a1, da, 0, 0, 0);
            db = __builtin_amdgcn_mfma_i32_16x16x64_i8(wsb1[ws], b1, db, 0, 0, 0);
            int sh = ish + 6 - 2 * ws;
            adc_acc(da, sh, acca);
            adc_acc(db, sh, accb);
        }
    }
}

__global__ __launch_bounds__(256, 4) void k_one(
    const float* __restrict__ x, const float* __restrict__ w,
    float* __restrict__ out)
{
    __shared__ __align__(16) unsigned char scrX[16 * SSTR];   // 11,008 B
    __shared__ __align__(16) unsigned char uni[32 * SSTR];    // 22,016: xs2 (14,592) then scrW
    __shared__ __align__(16) int pacc[2][64][4];              // 2,048
    __shared__ float xsc[16], xof[16], xsm[16];
    __shared__ float wscl[32], wofl[32], wsml[32];

    float* xs2 = (float*)uni;            // [64][57], phases A/B only
    unsigned char* scrW = uni;           // 32 rows x SSTR, phases C/D

    int tid = threadIdx.x, wv = tid >> 6, lane = tid & 63;
    int g = lane >> 4, i16 = lane & 15;
    int blk = blockIdx.x;                // 0..1567
    int rtile = blk >> 2, cq = blk & 3;
    int b = rtile >= 196 ? 1 : 0;
    int pos0 = (rtile - 196 * b) * 16;   // flat h*56+w of first row
    const float* xb = x + (size_t)(b * 64) * 3136;

    // ---- phase A: stage x stripe (flat-position trick, coalesced runs)
    for (int i = tid; i < 64 * 54; i += 256) {
        int cin = i / 54, rem = i - cin * 54;
        int kh = rem / 18;
        int gg = pos0 + (rem - kh * 18) - 1;
        float vv = 0.f;
        if (gg >= 0 && gg < 3136) {
            int hg = gg / 56, wg = gg - hg * 56;
            int r = hg - 1 + kh;
            if (r >= 0 && r < 56) vv = xb[cin * 3136 + r * 56 + wg];
        }
        xs2[cin * 57 + rem] = vv;
    }
    zero_pad_row(scrX, tid);             // 16 rows x 16 pad dwords
    __syncthreads();

    // ---- phase B: x quantization, 16 lane-groups, 1 row each
    {
        int i = wv * 4 + g;              // tile-local row 0..15
        int pos = pos0 + i;
        int w_ = pos - (pos / 56) * 56;
        float v[36];
#pragma unroll
        for (int m = 0; m < 36; m++) {
            int r9 = m % 9, kh = r9 / 3, kw = r9 - kh * 3;
            int cin = i16 * 4 + m / 9;
            int ww = w_ - 1 + kw;
            v[m] = (ww >= 0 && ww < 56) ? xs2[cin * 57 + kh * 18 + i + kw] : 0.f;
        }
        quant36(v, scrX + i * SSTR, i16, xsc, xof, xsm, i);
    }
    __syncthreads();                     // xs2 reads done; scrW (alias) writable

    // ---- phase C: w quantization for this block's 2 ctiles (32 rows)
    for (int idx = tid; idx < 512; idx += 256) zero_pad_row(scrW, idx);
    {
        int g16 = wv * 4 + g;
#pragma unroll
        for (int q = 0; q < 2; q++) {
            int rl = g16 * 2 + q;            // local w row 0..31
            int row = cq * 32 + rl;          // global w row
            const float* wr = w + (size_t)row * KDIM + i16 * 36;
            float v[36];
#pragma unroll
            for (int d = 0; d < 9; d++) {
                f32x4 t = *(const f32x4*)(wr + d * 4);
                v[d*4+0] = t[0]; v[d*4+1] = t[1]; v[d*4+2] = t[2]; v[d*4+3] = t[3];
            }
            quant36(v, scrW + rl * SSTR, i16, wscl, wofl, wsml, rl);
        }
    }
    __syncthreads();

    // ---- phase D: wave = (ctl_l = wv>>1, khalf = wv&1). khalf0: chunks 0-2,
    // khalf1: chunks 3-4 + combine + epilogue. Swapped operands (A=W, B=X):
    // C/D col (lane&15) = x position -> coalesced stores. Fragments read
    // directly from scratch: row = lane&15, col = chunk*128 + ks*64 + g*16.
    int ctl_l = wv >> 1, khalf = wv & 1;
    const unsigned char* xp = scrX + i16 * SSTR + g * 16;
    const unsigned char* wp = scrW + (ctl_l * 16 + i16) * SSTR + g * 16;

    i32x4 acc = {0, 0, 0, 0};
    if (khalf == 0) {
        i32x4 acc2 = {0, 0, 0, 0};
        chunk2(xp, wp, 0, 1, acc, acc2);
        chunk1(xp, wp, 2, acc);
#pragma unroll
        for (int r = 0; r < 4; r++) acc[r] += acc2[r];   // integer, exact
        *(i32x4*)&pacc[ctl_l][lane][0] = acc;
    } else {
        i32x4 acc2 = {0, 0, 0, 0};
        chunk2(xp, wp, 3, 4, acc, acc2);
#pragma unroll
        for (int r = 0; r < 4; r++) acc[r] += acc2[r];
    }
    __syncthreads();

    if (khalf == 1) {
        i32x4 p = *(const i32x4*)&pacc[ctl_l][lane][0];
#pragma unroll
        for (int r = 0; r < 4; r++) acc[r] += p[r];      // chunk-sum, exact

        float xs_ = xsc[i16], xo = xof[i16], xsv = xsm[i16];
        int hw = pos0 + i16;
#pragma unroll
        for (int r = 0; r < 4; r++) {
            int rl = ctl_l * 16 + g * 4 + r;             // local w row
            int wrow = cq * 32 + rl;
            float tt = ((float)acc[r] * xs_) * wscl[rl];
            float res = ((tt + xo * wsml[rl]) + wofl[rl] * xsv)
                      - (xo * wofl[rl]) * 576.0f;
            out[(size_t)(b * 128 + wrow) * 3136 + hw] = res;
        }
    }
}

extern "C" void kernel_launch(void* const* d_in, const int* in_sizes, int n_in,
                              void* d_out, int out_size, void* d_ws, size_t ws_size,
                              hipStream_t stream) {
    const float* x = (const float*)d_in[0];   // [2][64][56][56]
    const float* w = (const float*)d_in[1];   // [128][64][3][3]
    float* out = (float*)d_out;               // [2][128][56][56]

    hipLaunchKernelGGL(k_one, dim3(1568), dim3(256), 0, stream, x, w, out);
}

// Round 11
// 37.119 us; speedup vs baseline: 1.5581x; 1.5581x over previous
//
#include <hip/hip_runtime.h>

// ConvDatapath: bit-serial crossbar conv with per-chunk ADC quantization.
// k_q: quantize x (392 blocks, 16 rows each) and w (8 blocks) exactly ONCE
//      into fragment-layout Xq/Wq in d_ws (conflict-free LDS scratch, b128
//      coalesced copy-out). Scales/offsets/sums to global arrays.
// k_d: 1568 blocks x 256 thr; wave = (tile, khalf). khalf0: chunks 0-2,
//      khalf1: chunks 3-4 + LDS partial combine + epilogue. 4 per-ws
//      accumulators keep 4 MFMA->ADC chains in flight (integer-exact).
// Nx = 6272, Ny = 128, K = 576 (5 chunks of 116, padded to 128).

#define KDIM  576
#define NPB   116
#define SSTR  688    // scratch row stride: 43*16 -> b128-aligned, 172 dw % 32 = 12

typedef int i32x4 __attribute__((ext_vector_type(4)));
typedef float f32x4 __attribute__((ext_vector_type(4)));

__device__ __forceinline__ i32x4 slice2b(i32x4 v, int sh) {
    i32x4 r;
    r[0] = (int)(((unsigned)v[0] >> sh) & 0x03030303u);
    r[1] = (int)(((unsigned)v[1] >> sh) & 0x03030303u);
    r[2] = (int)(((unsigned)v[2] >> sh) & 0x03030303u);
    r[3] = (int)(((unsigned)v[3] >> sh) & 0x03030303u);
    return r;
}

// quantize one row spread over a 16-lane group (lane i16 holds k=36*i16..+35,
// k-ordered). Stats via 4-step shuffle (exact); 9 dword-aligned b32 writes,
// col = k + 12*chunk (i.e. chunk*128 + k%116).
__device__ __forceinline__ void quant36(const float (&v)[36], unsigned char* rowp,
                                        int i16, float* sc, float* of,
                                        float* sm_, int sidx)
{
    float mn = v[0], mx = v[0], sm = 0.f;
#pragma unroll
    for (int m = 0; m < 36; m++) { mn = fminf(mn, v[m]); mx = fmaxf(mx, v[m]); sm += v[m]; }
#pragma unroll
    for (int off = 1; off < 16; off <<= 1) {
        mn = fminf(mn, __shfl_xor(mn, off));
        mx = fmaxf(mx, __shfl_xor(mx, off));
        sm += __shfl_xor(sm, off);
    }
    float step = (mx - mn) / 255.0f;
    if (i16 == 0) { sc[sidx] = step; of[sidx] = mn; sm_[sidx] = sm; }
    int k0 = i16 * 36;
#pragma unroll
    for (int d = 0; d < 9; d++) {
        unsigned int dw = 0;
#pragma unroll
        for (int mb = 0; mb < 4; mb++) {
            int q = (int)rintf((v[d * 4 + mb] - mn) / step);
            q = q < 0 ? 0 : (q > 255 ? 255 : q);
            dw |= (unsigned)q << (8 * mb);
        }
        int kd = k0 + d * 4;
        int ch = kd / NPB;
        *(unsigned int*)(rowp + kd + 12 * ch) = dw;
    }
}

// zero the K-pad dwords of scratch row (idx>>4), pad dword (idx&15)
__device__ __forceinline__ void zero_pad_row(unsigned char* scr, int idx) {
    int rl = idx >> 4, dwp = idx & 15;
    int col = dwp < 12 ? (dwp / 3) * 128 + 116 + (dwp % 3) * 4
                       : 624 + (dwp - 12) * 4;
    *(unsigned int*)(scr + rl * SSTR + col) = 0u;
}

// copy 16-row scratch -> linear fragment tile (10,240 B) in global.
// dst 16B-run dst16 = ch*128 + ks*64 + lgrp*16 + rl; src row rl, col u*16
// (u = ch*8 + ks*4 + lgrp). Store coalesced; src reads ~2-way (free).
__device__ __forceinline__ void copy_out(const unsigned char* scr,
                                         unsigned char* dst, int tid) {
    for (int idx = tid; idx < 640; idx += 256) {
        int u = idx >> 4, rl = idx & 15;
        int dst16 = (u >> 3) * 128 + ((u >> 2) & 1) * 64 + (u & 3) * 16 + rl;
        *(i32x4*)(dst + dst16 * 16) = *(const i32x4*)(scr + rl * SSTR + u * 16);
    }
}

// ---------------- kernel 1: one-time quantization of x and w ----------------
__global__ __launch_bounds__(256) void k_q(
    const float* __restrict__ x, const float* __restrict__ w,
    unsigned char* __restrict__ Xq, unsigned char* __restrict__ Wq,
    float* __restrict__ xscg, float* __restrict__ xofg, float* __restrict__ xsmg,
    float* __restrict__ wscg, float* __restrict__ wofg, float* __restrict__ wsmg)
{
    __shared__ float xs2[64 * 57];                      // [cin][kh*18+c]
    __shared__ __align__(16) unsigned char scr[16 * SSTR];

    int tid = threadIdx.x, wv = tid >> 6, lane = tid & 63;
    int g = lane >> 4, i16 = lane & 15;
    int blk = blockIdx.x;

    if (blk < 392) {
        // ---- x tile: stage stripe, quantize 16 rows, copy out
        int b = blk >= 196 ? 1 : 0;
        int pos0 = (blk - 196 * b) * 16;
        const float* xb = x + (size_t)(b * 64) * 3136;
        for (int i = tid; i < 64 * 54; i += 256) {
            int cin = i / 54, rem = i - cin * 54;
            int kh = rem / 18;
            int gg = pos0 + (rem - kh * 18) - 1;
            float vv = 0.f;
            if (gg >= 0 && gg < 3136) {
                int hg = gg / 56, wg = gg - hg * 56;
                int r = hg - 1 + kh;
                if (r >= 0 && r < 56) vv = xb[cin * 3136 + r * 56 + wg];
            }
            xs2[cin * 57 + rem] = vv;
        }
        zero_pad_row(scr, tid);
        __syncthreads();

        int i = wv * 4 + g;               // tile-local row 0..15
        int pos = pos0 + i;
        int w_ = pos - (pos / 56) * 56;
        float v[36];
#pragma unroll
        for (int m = 0; m < 36; m++) {
            int r9 = m % 9, kh = r9 / 3, kw = r9 - kh * 3;
            int cin = i16 * 4 + m / 9;
            int ww = w_ - 1 + kw;
            v[m] = (ww >= 0 && ww < 56) ? xs2[cin * 57 + kh * 18 + i + kw] : 0.f;
        }
        quant36(v, scr + i * SSTR, i16, xscg, xofg, xsmg, blk * 16 + i);
        __syncthreads();

        copy_out(scr, Xq + (size_t)blk * 10240, tid);
    } else {
        // ---- w tile (blocks 392..399): direct global reads, quantize 16 rows
        int ctile = blk - 392;
        zero_pad_row(scr, tid);
        int rl = wv * 4 + g;              // 0..15
        int row = ctile * 16 + rl;
        const float* wr = w + (size_t)row * KDIM + i16 * 36;
        float v[36];
#pragma unroll
        for (int d = 0; d < 9; d++) {
            f32x4 t = *(const f32x4*)(wr + d * 4);
            v[d*4+0] = t[0]; v[d*4+1] = t[1]; v[d*4+2] = t[2]; v[d*4+3] = t[3];
        }
        quant36(v, scr + rl * SSTR, i16, wscg, wofg, wsmg, row);
        __syncthreads();

        copy_out(scr, Wq + (size_t)ctile * 10240, tid);
    }
}

// ---------------- kernel 2: crossbar MFMA + ADC + dequant ----------------
// one chunk, accumulating into 4 per-ws accumulators (4 indep chains)
__device__ __forceinline__ void chunk_ws(const unsigned char* xt, const unsigned char* wt,
                                         int ch, int lane, i32x4 (&acc4)[4])
{
    const i32x4 zero = {0, 0, 0, 0};
    i32x4 x0 = *(const i32x4*)(xt + ch * 2048 + lane * 16);
    i32x4 x1 = *(const i32x4*)(xt + ch * 2048 + 1024 + lane * 16);
    i32x4 w0 = *(const i32x4*)(wt + ch * 2048 + lane * 16);
    i32x4 w1 = *(const i32x4*)(wt + ch * 2048 + 1024 + lane * 16);
    i32x4 ws0[4], ws1[4];
#pragma unroll
    for (int ws = 0; ws < 4; ws++) {
        ws0[ws] = slice2b(w0, 6 - 2 * ws);
        ws1[ws] = slice2b(w1, 6 - 2 * ws);
    }
#pragma unroll
    for (int is = 0; is < 4; is++) {
        int ish = 6 - 2 * is;
        i32x4 a0 = slice2b(x0, ish), a1 = slice2b(x1, ish);
#pragma unroll
        for (int ws = 0; ws < 4; ws++) {
            i32x4 d = __builtin_amdgcn_mfma_i32_16x16x64_i8(ws0[ws], a0, zero, 0, 0, 0);
            d = __builtin_amdgcn_mfma_i32_16x16x64_i8(ws1[ws], a1, d, 0, 0, 0);
            int sh = ish + 6 - 2 * ws;
#pragma unroll
            for (int r = 0; r < 4; r++) {
                int z = d[r];
                z = z > 1024 ? 1024 : z;                 // ADC clip (z >= 0)
                int t = (z >> 2) & 1;
                int r4 = (z + 1 + t) & ~3;               // round-half-even, mult of 4
                acc4[ws][r] += r4 << sh;                 // 2^(ish+wsh)
            }
        }
    }
}

__global__ __launch_bounds__(256) void k_d(
    const unsigned char* __restrict__ Xq, const unsigned char* __restrict__ Wq,
    const float* __restrict__ xscg, const float* __restrict__ xofg,
    const float* __restrict__ xsmg,
    const float* __restrict__ wscg, const float* __restrict__ wofg,
    const float* __restrict__ wsmg, float* __restrict__ out)
{
    __shared__ __align__(16) int pacc[2][64][4];

    int tid = threadIdx.x, wv = tid >> 6, lane = tid & 63;
    int g = lane >> 4, i16 = lane & 15;
    int blk = blockIdx.x;                 // 0..1567
    int ct = blk & 7, rp = blk >> 3;      // rp 0..195
    int tl = wv & 1, khalf = wv >> 1;
    int rtile = rp * 2 + tl;              // 0..391
    const unsigned char* xt = Xq + (size_t)rtile * 10240;
    const unsigned char* wt = Wq + (size_t)ct * 10240;

    i32x4 acc4[4] = {{0,0,0,0},{0,0,0,0},{0,0,0,0},{0,0,0,0}};
    if (khalf == 0) {
        chunk_ws(xt, wt, 0, lane, acc4);
        chunk_ws(xt, wt, 1, lane, acc4);
        chunk_ws(xt, wt, 2, lane, acc4);
    } else {
        chunk_ws(xt, wt, 3, lane, acc4);
        chunk_ws(xt, wt, 4, lane, acc4);
    }
    i32x4 acc;
#pragma unroll
    for (int r = 0; r < 4; r++)
        acc[r] = (acc4[0][r] + acc4[1][r]) + (acc4[2][r] + acc4[3][r]);  // exact

    if (khalf == 0) *(i32x4*)&pacc[tl][lane][0] = acc;
    __syncthreads();

    if (khalf == 1) {
        i32x4 p = *(const i32x4*)&pacc[tl][lane][0];
#pragma unroll
        for (int r = 0; r < 4; r++) acc[r] += p[r];      // chunk-sum, exact

        // epilogue: D[row = w-row (g*4+r), col = x-row (i16)]; 64B coalesced
        int b = rtile >= 196 ? 1 : 0;
        int xrow = rtile * 16 + i16;
        float xs_ = xscg[xrow], xo = xofg[xrow], xsv = xsmg[xrow];
        int hw = (rtile - 196 * b) * 16 + i16;
#pragma unroll
        for (int r = 0; r < 4; r++) {
            int wrow = ct * 16 + g * 4 + r;
            float tt = ((float)acc[r] * xs_) * wscg[wrow];
            float res = ((tt + xo * wsmg[wrow]) + wofg[wrow] * xsv)
                      - (xo * wofg[wrow]) * 576.0f;
            out[(size_t)(b * 128 + wrow) * 3136 + hw] = res;
        }
    }
}

extern "C" void kernel_launch(void* const* d_in, const int* in_sizes, int n_in,
                              void* d_out, int out_size, void* d_ws, size_t ws_size,
                              hipStream_t stream) {
    const float* x = (const float*)d_in[0];   // [2][64][56][56]
    const float* w = (const float*)d_in[1];   // [128][64][3][3]
    float* out = (float*)d_out;               // [2][128][56][56]

    unsigned char* Xq = (unsigned char*)d_ws;          // 392*10,240 = 4,014,080 B
    unsigned char* Wq = Xq + (size_t)392 * 10240;      // 8*10,240   = 81,920 B
    float* xsc = (float*)(Wq + 8 * 10240);
    float* xof = xsc + 6272;
    float* xsm = xof + 6272;
    float* wsc = xsm + 6272;
    float* wof = wsc + 128;
    float* wsm = wof + 128;

    hipLaunchKernelGGL(k_q, dim3(400), dim3(256), 0, stream,
                       x, w, Xq, Wq, xsc, xof, xsm, wsc, wof, wsm);
    hipLaunchKernelGGL(k_d, dim3(1568), dim3(256), 0, stream,
                       Xq, Wq, xsc, xof, xsm, wsc, wof, wsm, out);
}